// Round 4
// baseline (646.905 us; speedup 1.0000x reference)
//
#include <hip/hip_runtime.h>
#include <hip/hip_bf16.h>

// Problem constants: T=8192, H=1024, D=1024, E=8, 2D=2048, K2=E*D=8192
#define T_DIM 8192
#define H_DIM 1024
#define D_DIM 1024
#define E_DIM 8
#define TWO_D 2048
#define K2 8192

#define ALPHA_C 1.702f
#define LIMIT_C 7.0f

typedef __attribute__((ext_vector_type(8))) short s8v;   // 8 bf16 = 4 VGPRs
typedef __attribute__((ext_vector_type(4))) float f4v;   // MFMA accumulator

__device__ __forceinline__ void g2l16(const void* g, void* l) {
    // async global->LDS, 16B per lane; LDS dest = wave-uniform base + lane*16
    __builtin_amdgcn_global_load_lds((const __attribute__((address_space(1))) void*)g,
                                     (__attribute__((address_space(3))) void*)l, 16, 0, 0);
}

__device__ __forceinline__ unsigned short f2bf(float f) {
    __hip_bfloat16 h = __float2bfloat16(f);
    return __builtin_bit_cast(unsigned short, h);
}

// ---------------- convert kernels ----------------

__global__ void f32_to_bf16_kernel(const float* __restrict__ in,
                                   unsigned short* __restrict__ out, size_t n) {
    size_t i = ((size_t)blockIdx.x * blockDim.x + threadIdx.x) * 4;
    if (i + 3 < n) {
        float4 v = *(const float4*)(in + i);
        ushort4 o;
        o.x = f2bf(v.x); o.y = f2bf(v.y); o.z = f2bf(v.z); o.w = f2bf(v.w);
        *(ushort4*)(out + i) = o;
    }
}

// out[b*obs + remap(c)*ors + r] = bf16(in[b*ibs + r*cols + c]); 32x32 tiles.
// remap==1: c -> (c&~31) + (c&1)*16 + ((c>>1)&15)   (gate/up 16-col deinterleave)
__global__ void transpose_conv_kernel(const float* __restrict__ in,
                                      unsigned short* __restrict__ out,
                                      int cols, size_t ibs, size_t obs, size_t ors,
                                      int remap) {
    __shared__ float t[32][33];
    const int b = blockIdx.z;
    const int c0 = blockIdx.x * 32, r0 = blockIdx.y * 32;
    const int tx = threadIdx.x & 31, ty = threadIdx.x >> 5;  // ty in 0..7
    const float* ip = in + (size_t)b * ibs;
    #pragma unroll
    for (int i = 0; i < 4; ++i)
        t[ty + i * 8][tx] = ip[(size_t)(r0 + ty + i * 8) * cols + c0 + tx];
    __syncthreads();
    unsigned short* op = out + (size_t)b * obs;
    #pragma unroll
    for (int i = 0; i < 4; ++i) {
        int c = c0 + ty + i * 8;
        int nc = remap ? ((c & ~31) + ((c & 1) << 4) + ((c >> 1) & 15)) : c;
        op[(size_t)nc * ors + r0 + tx] = f2bf(t[tx][ty + i * 8]);
    }
}

// out[t][h] = sum_e rw[t][e] * b3[e][h]  (init for gemm2's atomicAdd)
__global__ void bias_combine_kernel(const float* __restrict__ rw,
                                    const float* __restrict__ b3,
                                    float* __restrict__ out) {
    const int t = blockIdx.x;
    const int h = threadIdx.x * 4;
    float r[E_DIM];
    #pragma unroll
    for (int e = 0; e < E_DIM; ++e) r[e] = rw[(size_t)t * E_DIM + e];
    float4 v = {0.f, 0.f, 0.f, 0.f};
    #pragma unroll
    for (int e = 0; e < E_DIM; ++e) {
        float4 b = *(const float4*)(b3 + (size_t)e * H_DIM + h);
        v.x += r[e] * b.x; v.y += r[e] * b.y; v.z += r[e] * b.z; v.w += r[e] * b.w;
    }
    *(float4*)(out + (size_t)t * H_DIM + h) = v;
}

// ---------------- GEMM1: gu = hs @ W1[e] + b1[e]; act2 = rw*(up+1)*glu ----------------
// BK=64, XOR-swizzled LDS chunks. A: hsb [T][H] bf16. B: w1b [E][2D'][H] bf16
// (deinterleaved B^T). Output: act2 [T][E*D] bf16.
// Grid: (x=m fastest, y=n, z=e) so 8 consecutive blocks (8 XCDs) share one B n-tile.

__global__ __launch_bounds__(256, 2) void gemm1_kernel(
    const short* __restrict__ Ag0,      // hsb
    const short* __restrict__ Bg0,      // w1b
    const float* __restrict__ b1,       // [E][2D] original interleaved
    const float* __restrict__ rw,       // [T][E]
    __hip_bfloat16* __restrict__ act2)  // [T][E*D]
{
    const int e = blockIdx.z;
    const int mBase = blockIdx.x * 128;
    const int nBase = blockIdx.y * 128;
    const int tid = threadIdx.x;
    const int lane = tid & 63;
    const int wave = tid >> 6;
    const int wm = wave >> 1, wn = wave & 1;
    const int cq = lane & 15, quad = lane >> 4;

    __shared__ __align__(16) short As[128 * 64];
    __shared__ __align__(16) short Bs[128 * 64];

    const short* Ag = Ag0 + (size_t)mBase * H_DIM;
    const short* Bg = Bg0 + ((size_t)e * TWO_D + nBase) * H_DIM;

    f4v acc[4][4];
    #pragma unroll
    for (int mt = 0; mt < 4; ++mt)
        #pragma unroll
        for (int nt = 0; nt < 4; ++nt)
            acc[mt][nt] = (f4v){0.f, 0.f, 0.f, 0.f};

    const int srow8 = lane >> 3;                 // 0..7
    const int gco = ((lane & 7) ^ srow8) * 8;    // swizzled global k-offset (elements)
    const int cq7 = cq & 7;

    for (int k0 = 0; k0 < H_DIM; k0 += 64) {
        #pragma unroll
        for (int i = 0; i < 4; ++i) {
            const int r = wave * 32 + i * 8 + srow8;
            g2l16(Ag + (size_t)r * H_DIM + k0 + gco, As + (wave * 32 + i * 8) * 64);
            g2l16(Bg + (size_t)r * H_DIM + k0 + gco, Bs + (wave * 32 + i * 8) * 64);
        }
        __syncthreads();
        #pragma unroll
        for (int h = 0; h < 2; ++h) {
            s8v af[4], bf[4];
            const int pc = (((h << 2) + quad) ^ cq7) * 8;  // phys chunk offset (elements)
            #pragma unroll
            for (int i = 0; i < 4; ++i) {
                af[i] = *(const s8v*)(As + (wm * 64 + i * 16 + cq) * 64 + pc);
                bf[i] = *(const s8v*)(Bs + (wn * 64 + i * 16 + cq) * 64 + pc);
            }
            #pragma unroll
            for (int mt = 0; mt < 4; ++mt)
                #pragma unroll
                for (int nt = 0; nt < 4; ++nt)
                    acc[mt][nt] = __builtin_amdgcn_mfma_f32_16x16x32_bf16(
                        af[mt], bf[nt], acc[mt][nt], 0, 0, 0);
        }
        __syncthreads();
    }

    // epilogue: even nt tile = gate, odd nt tile = up for the same D-cols.
    float rwv[4][4];
    #pragma unroll
    for (int mt = 0; mt < 4; ++mt)
        #pragma unroll
        for (int r = 0; r < 4; ++r)
            rwv[mt][r] = rw[(size_t)(mBase + wm * 64 + mt * 16 + quad * 4 + r) * E_DIM + e];

    #pragma unroll
    for (int p = 0; p < 2; ++p) {
        const int j = (((nBase + wn * 64 + p * 32) >> 5) << 4) + cq;   // D-col in [0,1024)
        const float gb = b1[(size_t)e * TWO_D + 2 * j];
        const float ub = b1[(size_t)e * TWO_D + 2 * j + 1];
        #pragma unroll
        for (int mt = 0; mt < 4; ++mt) {
            #pragma unroll
            for (int r = 0; r < 4; ++r) {
                float gate = acc[mt][2 * p][r] + gb;
                float up   = acc[mt][2 * p + 1][r] + ub;
                gate = fminf(gate, LIMIT_C);
                up = fminf(fmaxf(up, -LIMIT_C), LIMIT_C);
                float glu = gate / (1.f + __expf(-ALPHA_C * gate));
                float a = (up + 1.f) * glu * rwv[mt][r];
                const int row = mBase + wm * 64 + mt * 16 + quad * 4 + r;
                act2[(size_t)row * K2 + (size_t)e * D_DIM + j] = __float2bfloat16(a);
            }
        }
    }
}

// ---------------- GEMM2 (split-K=4, XCD-pinned n): out += act2 @ W3stack ----------------
// A: act2 [T][8192] bf16. B: w3b [H][8192] bf16 (B^T). Out fp32 [T][H] via atomicAdd
// (pre-initialized with sum_e rw*b3). BK=64, same swizzle as gemm1.
// Flat 1D grid, id = blockIdx.x: n = id&7 (== XCD under round-robin → B column
// L2-pinned), m = (id>>3)&63 (same A-tile hits all 8 XCDs simultaneously → L3 share),
// k = id>>9.

#define KSLICE 2048

__global__ __launch_bounds__(256, 2) void gemm2_kernel(
    const short* __restrict__ Ag0,     // act2
    const short* __restrict__ Bg0,     // w3b
    float* __restrict__ out)           // [T][H]
{
    const int id = blockIdx.x;
    const int nBase = (id & 7) * 128;
    const int mBase = ((id >> 3) & 63) * 128;
    const int kBase = (id >> 9) * KSLICE;
    const int tid = threadIdx.x;
    const int lane = tid & 63;
    const int wave = tid >> 6;
    const int wm = wave >> 1, wn = wave & 1;
    const int cq = lane & 15, quad = lane >> 4;

    __shared__ __align__(16) short As[128 * 64];
    __shared__ __align__(16) short Bs[128 * 64];

    const short* Ag = Ag0 + (size_t)mBase * K2;
    const short* Bg = Bg0 + (size_t)nBase * K2;

    f4v acc[4][4];
    #pragma unroll
    for (int mt = 0; mt < 4; ++mt)
        #pragma unroll
        for (int nt = 0; nt < 4; ++nt)
            acc[mt][nt] = (f4v){0.f, 0.f, 0.f, 0.f};

    const int srow8 = lane >> 3;
    const int gco = ((lane & 7) ^ srow8) * 8;
    const int cq7 = cq & 7;

    for (int k0 = kBase; k0 < kBase + KSLICE; k0 += 64) {
        #pragma unroll
        for (int i = 0; i < 4; ++i) {
            const int r = wave * 32 + i * 8 + srow8;
            g2l16(Ag + (size_t)r * K2 + k0 + gco, As + (wave * 32 + i * 8) * 64);
            g2l16(Bg + (size_t)r * K2 + k0 + gco, Bs + (wave * 32 + i * 8) * 64);
        }
        __syncthreads();
        #pragma unroll
        for (int h = 0; h < 2; ++h) {
            s8v af[4], bf[4];
            const int pc = (((h << 2) + quad) ^ cq7) * 8;
            #pragma unroll
            for (int i = 0; i < 4; ++i) {
                af[i] = *(const s8v*)(As + (wm * 64 + i * 16 + cq) * 64 + pc);
                bf[i] = *(const s8v*)(Bs + (wn * 64 + i * 16 + cq) * 64 + pc);
            }
            #pragma unroll
            for (int mt = 0; mt < 4; ++mt)
                #pragma unroll
                for (int nt = 0; nt < 4; ++nt)
                    acc[mt][nt] = __builtin_amdgcn_mfma_f32_16x16x32_bf16(
                        af[mt], bf[nt], acc[mt][nt], 0, 0, 0);
        }
        __syncthreads();
    }

    #pragma unroll
    for (int mt = 0; mt < 4; ++mt) {
        #pragma unroll
        for (int r = 0; r < 4; ++r) {
            const int row = mBase + wm * 64 + mt * 16 + quad * 4 + r;
            #pragma unroll
            for (int nt = 0; nt < 4; ++nt) {
                atomicAdd(out + (size_t)row * H_DIM + nBase + wn * 64 + nt * 16 + cq,
                          acc[mt][nt][r]);
            }
        }
    }
}

// ---------------- launch ----------------

extern "C" void kernel_launch(void* const* d_in, const int* in_sizes, int n_in,
                              void* d_out, int out_size, void* d_ws, size_t ws_size,
                              hipStream_t stream) {
    const float* hs = (const float*)d_in[0];   // [T,H]
    const float* rw = (const float*)d_in[1];   // [T,E]
    const float* w1 = (const float*)d_in[2];   // [E,H,2D]
    const float* b1 = (const float*)d_in[3];   // [E,2D]
    const float* w3 = (const float*)d_in[4];   // [E,D,H]
    const float* b3 = (const float*)d_in[5];   // [E,H]
    float* out = (float*)d_out;

    char* ws = (char*)d_ws;
    unsigned short* hsb  = (unsigned short*)(ws);                          // 16 MB
    unsigned short* w1b  = (unsigned short*)(ws + ((size_t)16 << 20));     // 32 MB
    unsigned short* w3b  = (unsigned short*)(ws + ((size_t)48 << 20));     // 16 MB
    unsigned short* act2 = (unsigned short*)(ws + ((size_t)64 << 20));     // 128 MB

    // 1) hs -> bf16
    {
        size_t n = (size_t)T_DIM * H_DIM;  // 8388608
        f32_to_bf16_kernel<<<dim3(n / (256 * 4)), dim3(256), 0, stream>>>(hs, hsb, n);
    }
    // 2) W1 [E][H][2D] -> w1b [E][2D'][H] bf16 with gate/up 16-col deinterleave
    transpose_conv_kernel<<<dim3(TWO_D / 32, H_DIM / 32, E_DIM), dim3(256), 0, stream>>>(
        w1, w1b, TWO_D, (size_t)H_DIM * TWO_D, (size_t)TWO_D * H_DIM, (size_t)H_DIM, 1);
    // 3) W3 [E][D][H] -> w3b [H][E*D] bf16  (out idx = b*D + c*(E*D) + r)
    transpose_conv_kernel<<<dim3(H_DIM / 32, D_DIM / 32, E_DIM), dim3(256), 0, stream>>>(
        w3, w3b, H_DIM, (size_t)D_DIM * H_DIM, (size_t)D_DIM, (size_t)K2, 0);
    // 4) GEMM1 + GLU epilogue -> act2  (x=m fastest for XCD B-sharing)
    gemm1_kernel<<<dim3(T_DIM / 128, TWO_D / 128, E_DIM), dim3(256), 0, stream>>>(
        (const short*)hsb, (const short*)w1b, b1, rw, (__hip_bfloat16*)act2);
    // 5) out = sum_e rw*b3  (init for atomics)
    bias_combine_kernel<<<dim3(T_DIM), dim3(H_DIM / 4), 0, stream>>>(rw, b3, out);
    // 6) GEMM2 split-K=4, XCD-pinned n, atomicAdd into out
    gemm2_kernel<<<dim3(8 * 64 * (K2 / KSLICE)), dim3(256), 0, stream>>>(
        (const short*)act2, (const short*)w3b, out);
}

// Round 5
// 629.194 us; speedup vs baseline: 1.0281x; 1.0281x over previous
//
#include <hip/hip_runtime.h>
#include <hip/hip_bf16.h>

// Problem constants: T=8192, H=1024, D=1024, E=8, 2D=2048, K2=E*D=8192
#define T_DIM 8192
#define H_DIM 1024
#define D_DIM 1024
#define E_DIM 8
#define TWO_D 2048
#define K2 8192

#define ALPHA_C 1.702f
#define LIMIT_C 7.0f

typedef __attribute__((ext_vector_type(8))) short s8v;   // 8 bf16 = 4 VGPRs
typedef __attribute__((ext_vector_type(4))) float f4v;   // MFMA accumulator

__device__ __forceinline__ void g2l16(const void* g, void* l) {
    // async global->LDS, 16B per lane; LDS dest = wave-uniform base + lane*16
    __builtin_amdgcn_global_load_lds((const __attribute__((address_space(1))) void*)g,
                                     (__attribute__((address_space(3))) void*)l, 16, 0, 0);
}

__device__ __forceinline__ unsigned short f2bf(float f) {
    __hip_bfloat16 h = __float2bfloat16(f);
    return __builtin_bit_cast(unsigned short, h);
}

// ---------------- convert kernels ----------------

__global__ void f32_to_bf16_kernel(const float* __restrict__ in,
                                   unsigned short* __restrict__ out, size_t n) {
    size_t i = ((size_t)blockIdx.x * blockDim.x + threadIdx.x) * 4;
    if (i + 3 < n) {
        float4 v = *(const float4*)(in + i);
        ushort4 o;
        o.x = f2bf(v.x); o.y = f2bf(v.y); o.z = f2bf(v.z); o.w = f2bf(v.w);
        *(ushort4*)(out + i) = o;
    }
}

// out[b*obs + remap(c)*ors + r] = bf16(in[b*ibs + r*cols + c]); 32x32 tiles.
// remap==1: c -> (c&~31) + (c&1)*16 + ((c>>1)&15)   (gate/up 16-col deinterleave)
__global__ void transpose_conv_kernel(const float* __restrict__ in,
                                      unsigned short* __restrict__ out,
                                      int cols, size_t ibs, size_t obs, size_t ors,
                                      int remap) {
    __shared__ float t[32][33];
    const int b = blockIdx.z;
    const int c0 = blockIdx.x * 32, r0 = blockIdx.y * 32;
    const int tx = threadIdx.x & 31, ty = threadIdx.x >> 5;  // ty in 0..7
    const float* ip = in + (size_t)b * ibs;
    #pragma unroll
    for (int i = 0; i < 4; ++i)
        t[ty + i * 8][tx] = ip[(size_t)(r0 + ty + i * 8) * cols + c0 + tx];
    __syncthreads();
    unsigned short* op = out + (size_t)b * obs;
    #pragma unroll
    for (int i = 0; i < 4; ++i) {
        int c = c0 + ty + i * 8;
        int nc = remap ? ((c & ~31) + ((c & 1) << 4) + ((c >> 1) & 15)) : c;
        op[(size_t)nc * ors + r0 + tx] = f2bf(t[tx][ty + i * 8]);
    }
}

// out[t][h] += partial[t][h] + sum_e rw[t][e]*b3[e][h]
__global__ void reduce_bias_kernel(const float* __restrict__ partial,
                                   const float* __restrict__ rw,
                                   const float* __restrict__ b3,
                                   float* __restrict__ out) {
    const int t = blockIdx.x;
    const int h = threadIdx.x * 4;
    float r[E_DIM];
    #pragma unroll
    for (int e = 0; e < E_DIM; ++e) r[e] = rw[(size_t)t * E_DIM + e];
    float4 v = *(const float4*)(out + (size_t)t * H_DIM + h);
    float4 p = *(const float4*)(partial + (size_t)t * H_DIM + h);
    v.x += p.x; v.y += p.y; v.z += p.z; v.w += p.w;
    #pragma unroll
    for (int e = 0; e < E_DIM; ++e) {
        float4 b = *(const float4*)(b3 + (size_t)e * H_DIM + h);
        v.x += r[e] * b.x; v.y += r[e] * b.y; v.z += r[e] * b.z; v.w += r[e] * b.w;
    }
    *(float4*)(out + (size_t)t * H_DIM + h) = v;
}

// ---------------- GEMM1: gu = hs @ W1[e] + b1[e]; act2 = rw*(up+1)*glu ----------------
// BK=64, XOR-swizzled LDS chunks. A: hsb [T][H] bf16. B: w1b [E][2D'][H] bf16
// (deinterleaved B^T). Output: act2 [T][E*D] bf16.
// Grid: (x=m fastest, y=n, z=e) so 8 consecutive blocks (8 XCDs) share one B n-tile.

__global__ __launch_bounds__(256, 2) void gemm1_kernel(
    const short* __restrict__ Ag0,      // hsb
    const short* __restrict__ Bg0,      // w1b
    const float* __restrict__ b1,       // [E][2D] original interleaved
    const float* __restrict__ rw,       // [T][E]
    __hip_bfloat16* __restrict__ act2)  // [T][E*D]
{
    const int e = blockIdx.z;
    const int mBase = blockIdx.x * 128;
    const int nBase = blockIdx.y * 128;
    const int tid = threadIdx.x;
    const int lane = tid & 63;
    const int wave = tid >> 6;
    const int wm = wave >> 1, wn = wave & 1;
    const int cq = lane & 15, quad = lane >> 4;

    __shared__ __align__(16) short As[128 * 64];
    __shared__ __align__(16) short Bs[128 * 64];

    const short* Ag = Ag0 + (size_t)mBase * H_DIM;
    const short* Bg = Bg0 + ((size_t)e * TWO_D + nBase) * H_DIM;

    f4v acc[4][4];
    #pragma unroll
    for (int mt = 0; mt < 4; ++mt)
        #pragma unroll
        for (int nt = 0; nt < 4; ++nt)
            acc[mt][nt] = (f4v){0.f, 0.f, 0.f, 0.f};

    const int srow8 = lane >> 3;                 // 0..7
    const int gco = ((lane & 7) ^ srow8) * 8;    // swizzled global k-offset (elements)
    const int cq7 = cq & 7;

    for (int k0 = 0; k0 < H_DIM; k0 += 64) {
        #pragma unroll
        for (int i = 0; i < 4; ++i) {
            const int r = wave * 32 + i * 8 + srow8;
            g2l16(Ag + (size_t)r * H_DIM + k0 + gco, As + (wave * 32 + i * 8) * 64);
            g2l16(Bg + (size_t)r * H_DIM + k0 + gco, Bs + (wave * 32 + i * 8) * 64);
        }
        __syncthreads();
        #pragma unroll
        for (int h = 0; h < 2; ++h) {
            s8v af[4], bf[4];
            const int pc = (((h << 2) + quad) ^ cq7) * 8;  // phys chunk offset (elements)
            #pragma unroll
            for (int i = 0; i < 4; ++i) {
                af[i] = *(const s8v*)(As + (wm * 64 + i * 16 + cq) * 64 + pc);
                bf[i] = *(const s8v*)(Bs + (wn * 64 + i * 16 + cq) * 64 + pc);
            }
            #pragma unroll
            for (int mt = 0; mt < 4; ++mt)
                #pragma unroll
                for (int nt = 0; nt < 4; ++nt)
                    acc[mt][nt] = __builtin_amdgcn_mfma_f32_16x16x32_bf16(
                        af[mt], bf[nt], acc[mt][nt], 0, 0, 0);
        }
        __syncthreads();
    }

    // epilogue: even nt tile = gate, odd nt tile = up for the same D-cols.
    float rwv[4][4];
    #pragma unroll
    for (int mt = 0; mt < 4; ++mt)
        #pragma unroll
        for (int r = 0; r < 4; ++r)
            rwv[mt][r] = rw[(size_t)(mBase + wm * 64 + mt * 16 + quad * 4 + r) * E_DIM + e];

    #pragma unroll
    for (int p = 0; p < 2; ++p) {
        const int j = (((nBase + wn * 64 + p * 32) >> 5) << 4) + cq;   // D-col in [0,1024)
        const float gb = b1[(size_t)e * TWO_D + 2 * j];
        const float ub = b1[(size_t)e * TWO_D + 2 * j + 1];
        #pragma unroll
        for (int mt = 0; mt < 4; ++mt) {
            #pragma unroll
            for (int r = 0; r < 4; ++r) {
                float gate = acc[mt][2 * p][r] + gb;
                float up   = acc[mt][2 * p + 1][r] + ub;
                gate = fminf(gate, LIMIT_C);
                up = fminf(fmaxf(up, -LIMIT_C), LIMIT_C);
                float glu = gate / (1.f + __expf(-ALPHA_C * gate));
                float a = (up + 1.f) * glu * rwv[mt][r];
                const int row = mBase + wm * 64 + mt * 16 + quad * 4 + r;
                act2[(size_t)row * K2 + (size_t)e * D_DIM + j] = __float2bfloat16(a);
            }
        }
    }
}

// ---------------- GEMM2 (split-K=2, no atomics): partial sums, plain stores --------
// A: act2 [T][8192] bf16. B: w3b [H][8192] bf16 (B^T). k-slice 0 -> out (fp32),
// k-slice 1 -> partial (fp32). BK=64, same swizzle as gemm1.
// Flat 1D grid, id: n = id&7 (XCD-pinned B column), m = (id>>3)&63 (A-tile shared
// across 8 XCDs simultaneously via L3), k = id>>9.

#define KSLICE 4096

__global__ __launch_bounds__(256, 2) void gemm2_kernel(
    const short* __restrict__ Ag0,     // act2
    const short* __restrict__ Bg0,     // w3b
    float* __restrict__ out,           // [T][H] (k-slice 0)
    float* __restrict__ partial)       // [T][H] (k-slice 1)
{
    const int id = blockIdx.x;
    const int nBase = (id & 7) * 128;
    const int mBase = ((id >> 3) & 63) * 128;
    const int kIdx = id >> 9;
    const int kBase = kIdx * KSLICE;
    const int tid = threadIdx.x;
    const int lane = tid & 63;
    const int wave = tid >> 6;
    const int wm = wave >> 1, wn = wave & 1;
    const int cq = lane & 15, quad = lane >> 4;

    __shared__ __align__(16) short As[128 * 64];
    __shared__ __align__(16) short Bs[128 * 64];

    const short* Ag = Ag0 + (size_t)mBase * K2;
    const short* Bg = Bg0 + (size_t)nBase * K2;

    f4v acc[4][4];
    #pragma unroll
    for (int mt = 0; mt < 4; ++mt)
        #pragma unroll
        for (int nt = 0; nt < 4; ++nt)
            acc[mt][nt] = (f4v){0.f, 0.f, 0.f, 0.f};

    const int srow8 = lane >> 3;
    const int gco = ((lane & 7) ^ srow8) * 8;
    const int cq7 = cq & 7;

    for (int k0 = kBase; k0 < kBase + KSLICE; k0 += 64) {
        #pragma unroll
        for (int i = 0; i < 4; ++i) {
            const int r = wave * 32 + i * 8 + srow8;
            g2l16(Ag + (size_t)r * K2 + k0 + gco, As + (wave * 32 + i * 8) * 64);
            g2l16(Bg + (size_t)r * K2 + k0 + gco, Bs + (wave * 32 + i * 8) * 64);
        }
        __syncthreads();
        #pragma unroll
        for (int h = 0; h < 2; ++h) {
            s8v af[4], bf[4];
            const int pc = (((h << 2) + quad) ^ cq7) * 8;
            #pragma unroll
            for (int i = 0; i < 4; ++i) {
                af[i] = *(const s8v*)(As + (wm * 64 + i * 16 + cq) * 64 + pc);
                bf[i] = *(const s8v*)(Bs + (wn * 64 + i * 16 + cq) * 64 + pc);
            }
            #pragma unroll
            for (int mt = 0; mt < 4; ++mt)
                #pragma unroll
                for (int nt = 0; nt < 4; ++nt)
                    acc[mt][nt] = __builtin_amdgcn_mfma_f32_16x16x32_bf16(
                        af[mt], bf[nt], acc[mt][nt], 0, 0, 0);
        }
        __syncthreads();
    }

    float* dst = kIdx ? partial : out;
    #pragma unroll
    for (int mt = 0; mt < 4; ++mt) {
        #pragma unroll
        for (int r = 0; r < 4; ++r) {
            const int row = mBase + wm * 64 + mt * 16 + quad * 4 + r;
            #pragma unroll
            for (int nt = 0; nt < 4; ++nt) {
                dst[(size_t)row * H_DIM + nBase + wn * 64 + nt * 16 + cq] =
                    acc[mt][nt][r];
            }
        }
    }
}

// ---------------- launch ----------------

extern "C" void kernel_launch(void* const* d_in, const int* in_sizes, int n_in,
                              void* d_out, int out_size, void* d_ws, size_t ws_size,
                              hipStream_t stream) {
    const float* hs = (const float*)d_in[0];   // [T,H]
    const float* rw = (const float*)d_in[1];   // [T,E]
    const float* w1 = (const float*)d_in[2];   // [E,H,2D]
    const float* b1 = (const float*)d_in[3];   // [E,2D]
    const float* w3 = (const float*)d_in[4];   // [E,D,H]
    const float* b3 = (const float*)d_in[5];   // [E,H]
    float* out = (float*)d_out;

    char* ws = (char*)d_ws;
    unsigned short* hsb  = (unsigned short*)(ws);                          // 16 MB
    unsigned short* w1b  = (unsigned short*)(ws + ((size_t)16 << 20));     // 32 MB
    unsigned short* w3b  = (unsigned short*)(ws + ((size_t)48 << 20));     // 16 MB
    unsigned short* act2 = (unsigned short*)(ws + ((size_t)64 << 20));     // 128 MB
    // partial reuses hsb+half of w1b (dead after gemm1): 32 MB fp32 [T][H]
    float* partial = (float*)(ws);

    // 1) hs -> bf16
    {
        size_t n = (size_t)T_DIM * H_DIM;  // 8388608
        f32_to_bf16_kernel<<<dim3(n / (256 * 4)), dim3(256), 0, stream>>>(hs, hsb, n);
    }
    // 2) W1 [E][H][2D] -> w1b [E][2D'][H] bf16 with gate/up 16-col deinterleave
    transpose_conv_kernel<<<dim3(TWO_D / 32, H_DIM / 32, E_DIM), dim3(256), 0, stream>>>(
        w1, w1b, TWO_D, (size_t)H_DIM * TWO_D, (size_t)TWO_D * H_DIM, (size_t)H_DIM, 1);
    // 3) W3 [E][D][H] -> w3b [H][E*D] bf16  (out idx = b*D + c*(E*D) + r)
    transpose_conv_kernel<<<dim3(H_DIM / 32, D_DIM / 32, E_DIM), dim3(256), 0, stream>>>(
        w3, w3b, H_DIM, (size_t)D_DIM * H_DIM, (size_t)D_DIM, (size_t)K2, 0);
    // 4) GEMM1 + GLU epilogue -> act2  (x=m fastest for XCD B-sharing)
    gemm1_kernel<<<dim3(T_DIM / 128, TWO_D / 128, E_DIM), dim3(256), 0, stream>>>(
        (const short*)hsb, (const short*)w1b, b1, rw, (__hip_bfloat16*)act2);
    // 5) GEMM2 split-K=2: slice0 -> out, slice1 -> partial (hsb/w1b region, now dead)
    gemm2_kernel<<<dim3(8 * 64 * 2), dim3(256), 0, stream>>>(
        (const short*)act2, (const short*)w3b, out, partial);
    // 6) out += partial + sum_e rw*b3
    reduce_bias_kernel<<<dim3(T_DIM), dim3(H_DIM / 4), 0, stream>>>(partial, rw, b3, out);
}

// Round 6
// 623.405 us; speedup vs baseline: 1.0377x; 1.0093x over previous
//
#include <hip/hip_runtime.h>
#include <hip/hip_bf16.h>

// Problem constants: T=8192, H=1024, D=1024, E=8, 2D=2048, K2=E*D=8192
#define T_DIM 8192
#define H_DIM 1024
#define D_DIM 1024
#define E_DIM 8
#define TWO_D 2048
#define K2 8192

#define ALPHA_C 1.702f
#define LIMIT_C 7.0f

typedef __attribute__((ext_vector_type(8))) short s8v;   // 8 bf16 = 4 VGPRs
typedef __attribute__((ext_vector_type(4))) float f4v;   // MFMA accumulator

__device__ __forceinline__ void g2l16(const void* g, void* l) {
    // async global->LDS, 16B per lane; LDS dest = wave-uniform base + lane*16
    __builtin_amdgcn_global_load_lds((const __attribute__((address_space(1))) void*)g,
                                     (__attribute__((address_space(3))) void*)l, 16, 0, 0);
}

__device__ __forceinline__ unsigned short f2bf(float f) {
    __hip_bfloat16 h = __float2bfloat16(f);
    return __builtin_bit_cast(unsigned short, h);
}

__device__ __forceinline__ float bf2f(unsigned short u) {
    unsigned int x = ((unsigned int)u) << 16;
    return __builtin_bit_cast(float, x);
}

// ---------------- convert kernels ----------------

__global__ void f32_to_bf16_kernel(const float* __restrict__ in,
                                   unsigned short* __restrict__ out, size_t n) {
    size_t i = ((size_t)blockIdx.x * blockDim.x + threadIdx.x) * 4;
    if (i + 3 < n) {
        float4 v = *(const float4*)(in + i);
        ushort4 o;
        o.x = f2bf(v.x); o.y = f2bf(v.y); o.z = f2bf(v.z); o.w = f2bf(v.w);
        *(ushort4*)(out + i) = o;
    }
}

// out[b*obs + remap(c)*ors + r] = bf16(in[b*ibs + r*cols + c]); 32x32 tiles.
// remap==1: c -> (c&~31) + (c&1)*16 + ((c>>1)&15)   (gate/up 16-col deinterleave)
__global__ void transpose_conv_kernel(const float* __restrict__ in,
                                      unsigned short* __restrict__ out,
                                      int cols, size_t ibs, size_t obs, size_t ors,
                                      int remap) {
    __shared__ float t[32][33];
    const int b = blockIdx.z;
    const int c0 = blockIdx.x * 32, r0 = blockIdx.y * 32;
    const int tx = threadIdx.x & 31, ty = threadIdx.x >> 5;  // ty in 0..7
    const float* ip = in + (size_t)b * ibs;
    #pragma unroll
    for (int i = 0; i < 4; ++i)
        t[ty + i * 8][tx] = ip[(size_t)(r0 + ty + i * 8) * cols + c0 + tx];
    __syncthreads();
    unsigned short* op = out + (size_t)b * obs;
    #pragma unroll
    for (int i = 0; i < 4; ++i) {
        int c = c0 + ty + i * 8;
        int nc = remap ? ((c & ~31) + ((c & 1) << 4) + ((c >> 1) & 15)) : c;
        op[(size_t)nc * ors + r0 + tx] = f2bf(t[tx][ty + i * 8]);
    }
}

// out[t][h] += p0+p1+p2 (bf16 partials) + sum_e rw[t][e]*b3[e][h]
__global__ void reduce_bias_kernel(const unsigned short* __restrict__ p0,
                                   const unsigned short* __restrict__ p1,
                                   const unsigned short* __restrict__ p2,
                                   const float* __restrict__ rw,
                                   const float* __restrict__ b3,
                                   float* __restrict__ out) {
    const int t = blockIdx.x;
    const int h = threadIdx.x * 4;
    const size_t idx = (size_t)t * H_DIM + h;
    float r[E_DIM];
    #pragma unroll
    for (int e = 0; e < E_DIM; ++e) r[e] = rw[(size_t)t * E_DIM + e];
    float4 v = *(const float4*)(out + idx);
    ushort4 a = *(const ushort4*)(p0 + idx);
    ushort4 b = *(const ushort4*)(p1 + idx);
    ushort4 c = *(const ushort4*)(p2 + idx);
    v.x += bf2f(a.x) + bf2f(b.x) + bf2f(c.x);
    v.y += bf2f(a.y) + bf2f(b.y) + bf2f(c.y);
    v.z += bf2f(a.z) + bf2f(b.z) + bf2f(c.z);
    v.w += bf2f(a.w) + bf2f(b.w) + bf2f(c.w);
    #pragma unroll
    for (int e = 0; e < E_DIM; ++e) {
        float4 bb = *(const float4*)(b3 + (size_t)e * H_DIM + h);
        v.x += r[e] * bb.x; v.y += r[e] * bb.y; v.z += r[e] * bb.z; v.w += r[e] * bb.w;
    }
    *(float4*)(out + idx) = v;
}

// ---------------- GEMM1: gu = hs @ W1[e] + b1[e]; act2 = rw*(up+1)*glu ----------------
// BK=64, XOR-swizzled LDS chunks. A: hsb [T][H] bf16. B: w1b [E][2D'][H] bf16
// (deinterleaved B^T). Output: act2 [T][E*D] bf16.
// Grid: (x=m fastest, y=n, z=e) so 8 consecutive blocks (8 XCDs) share one B n-tile.

__global__ __launch_bounds__(256, 2) void gemm1_kernel(
    const short* __restrict__ Ag0,      // hsb
    const short* __restrict__ Bg0,      // w1b
    const float* __restrict__ b1,       // [E][2D] original interleaved
    const float* __restrict__ rw,       // [T][E]
    __hip_bfloat16* __restrict__ act2)  // [T][E*D]
{
    const int e = blockIdx.z;
    const int mBase = blockIdx.x * 128;
    const int nBase = blockIdx.y * 128;
    const int tid = threadIdx.x;
    const int lane = tid & 63;
    const int wave = tid >> 6;
    const int wm = wave >> 1, wn = wave & 1;
    const int cq = lane & 15, quad = lane >> 4;

    __shared__ __align__(16) short As[128 * 64];
    __shared__ __align__(16) short Bs[128 * 64];

    const short* Ag = Ag0 + (size_t)mBase * H_DIM;
    const short* Bg = Bg0 + ((size_t)e * TWO_D + nBase) * H_DIM;

    f4v acc[4][4];
    #pragma unroll
    for (int mt = 0; mt < 4; ++mt)
        #pragma unroll
        for (int nt = 0; nt < 4; ++nt)
            acc[mt][nt] = (f4v){0.f, 0.f, 0.f, 0.f};

    const int srow8 = lane >> 3;                 // 0..7
    const int gco = ((lane & 7) ^ srow8) * 8;    // swizzled global k-offset (elements)
    const int cq7 = cq & 7;

    for (int k0 = 0; k0 < H_DIM; k0 += 64) {
        #pragma unroll
        for (int i = 0; i < 4; ++i) {
            const int r = wave * 32 + i * 8 + srow8;
            g2l16(Ag + (size_t)r * H_DIM + k0 + gco, As + (wave * 32 + i * 8) * 64);
            g2l16(Bg + (size_t)r * H_DIM + k0 + gco, Bs + (wave * 32 + i * 8) * 64);
        }
        __syncthreads();
        #pragma unroll
        for (int h = 0; h < 2; ++h) {
            s8v af[4], bf[4];
            const int pc = (((h << 2) + quad) ^ cq7) * 8;  // phys chunk offset (elements)
            #pragma unroll
            for (int i = 0; i < 4; ++i) {
                af[i] = *(const s8v*)(As + (wm * 64 + i * 16 + cq) * 64 + pc);
                bf[i] = *(const s8v*)(Bs + (wn * 64 + i * 16 + cq) * 64 + pc);
            }
            #pragma unroll
            for (int mt = 0; mt < 4; ++mt)
                #pragma unroll
                for (int nt = 0; nt < 4; ++nt)
                    acc[mt][nt] = __builtin_amdgcn_mfma_f32_16x16x32_bf16(
                        af[mt], bf[nt], acc[mt][nt], 0, 0, 0);
        }
        __syncthreads();
    }

    // epilogue: even nt tile = gate, odd nt tile = up for the same D-cols.
    float rwv[4][4];
    #pragma unroll
    for (int mt = 0; mt < 4; ++mt)
        #pragma unroll
        for (int r = 0; r < 4; ++r)
            rwv[mt][r] = rw[(size_t)(mBase + wm * 64 + mt * 16 + quad * 4 + r) * E_DIM + e];

    #pragma unroll
    for (int p = 0; p < 2; ++p) {
        const int j = (((nBase + wn * 64 + p * 32) >> 5) << 4) + cq;   // D-col in [0,1024)
        const float gb = b1[(size_t)e * TWO_D + 2 * j];
        const float ub = b1[(size_t)e * TWO_D + 2 * j + 1];
        #pragma unroll
        for (int mt = 0; mt < 4; ++mt) {
            #pragma unroll
            for (int r = 0; r < 4; ++r) {
                float gate = acc[mt][2 * p][r] + gb;
                float up   = acc[mt][2 * p + 1][r] + ub;
                gate = fminf(gate, LIMIT_C);
                up = fminf(fmaxf(up, -LIMIT_C), LIMIT_C);
                float glu = gate / (1.f + __expf(-ALPHA_C * gate));
                float a = (up + 1.f) * glu * rwv[mt][r];
                const int row = mBase + wm * 64 + mt * 16 + quad * 4 + r;
                act2[(size_t)row * K2 + (size_t)e * D_DIM + j] = __float2bfloat16(a);
            }
        }
    }
}

// ---------------- GEMM2 (split-K=4, no atomics): slice0 -> out fp32, slices 1-3 ->
// bf16 partials. A: act2 [T][8192] bf16. B: w3b [H][8192] bf16 (B^T). BK=64, same
// swizzle as gemm1. Flat 1D grid, id: n = id&7 (XCD-pinned B column), m = (id>>3)&63
// (A-tile shared across 8 XCDs via L3), k = id>>9 in [0,4).

#define KSLICE 2048

__global__ __launch_bounds__(256, 2) void gemm2_kernel(
    const short* __restrict__ Ag0,     // act2
    const short* __restrict__ Bg0,     // w3b
    float* __restrict__ out,           // [T][H] (k-slice 0)
    unsigned short* __restrict__ p0,   // [T][H] bf16 (k-slice 1)
    unsigned short* __restrict__ p1,   // [T][H] bf16 (k-slice 2)
    unsigned short* __restrict__ p2)   // [T][H] bf16 (k-slice 3)
{
    const int id = blockIdx.x;
    const int nBase = (id & 7) * 128;
    const int mBase = ((id >> 3) & 63) * 128;
    const int kIdx = id >> 9;
    const int kBase = kIdx * KSLICE;
    const int tid = threadIdx.x;
    const int lane = tid & 63;
    const int wave = tid >> 6;
    const int wm = wave >> 1, wn = wave & 1;
    const int cq = lane & 15, quad = lane >> 4;

    __shared__ __align__(16) short As[128 * 64];
    __shared__ __align__(16) short Bs[128 * 64];

    const short* Ag = Ag0 + (size_t)mBase * K2;
    const short* Bg = Bg0 + (size_t)nBase * K2;

    f4v acc[4][4];
    #pragma unroll
    for (int mt = 0; mt < 4; ++mt)
        #pragma unroll
        for (int nt = 0; nt < 4; ++nt)
            acc[mt][nt] = (f4v){0.f, 0.f, 0.f, 0.f};

    const int srow8 = lane >> 3;
    const int gco = ((lane & 7) ^ srow8) * 8;
    const int cq7 = cq & 7;

    for (int k0 = kBase; k0 < kBase + KSLICE; k0 += 64) {
        #pragma unroll
        for (int i = 0; i < 4; ++i) {
            const int r = wave * 32 + i * 8 + srow8;
            g2l16(Ag + (size_t)r * K2 + k0 + gco, As + (wave * 32 + i * 8) * 64);
            g2l16(Bg + (size_t)r * K2 + k0 + gco, Bs + (wave * 32 + i * 8) * 64);
        }
        __syncthreads();
        #pragma unroll
        for (int h = 0; h < 2; ++h) {
            s8v af[4], bf[4];
            const int pc = (((h << 2) + quad) ^ cq7) * 8;
            #pragma unroll
            for (int i = 0; i < 4; ++i) {
                af[i] = *(const s8v*)(As + (wm * 64 + i * 16 + cq) * 64 + pc);
                bf[i] = *(const s8v*)(Bs + (wn * 64 + i * 16 + cq) * 64 + pc);
            }
            #pragma unroll
            for (int mt = 0; mt < 4; ++mt)
                #pragma unroll
                for (int nt = 0; nt < 4; ++nt)
                    acc[mt][nt] = __builtin_amdgcn_mfma_f32_16x16x32_bf16(
                        af[mt], bf[nt], acc[mt][nt], 0, 0, 0);
        }
        __syncthreads();
    }

    unsigned short* pdst = (kIdx == 1) ? p0 : (kIdx == 2) ? p1 : p2;
    #pragma unroll
    for (int mt = 0; mt < 4; ++mt) {
        #pragma unroll
        for (int r = 0; r < 4; ++r) {
            const int row = mBase + wm * 64 + mt * 16 + quad * 4 + r;
            const size_t idx = (size_t)row * H_DIM + nBase + wn * 64 + 16 * 0 + cq;
            #pragma unroll
            for (int nt = 0; nt < 4; ++nt) {
                const size_t o = (size_t)row * H_DIM + nBase + wn * 64 + nt * 16 + cq;
                if (kIdx == 0) out[o] = acc[mt][nt][r];
                else           pdst[o] = f2bf(acc[mt][nt][r]);
            }
            (void)idx;
        }
    }
}

// ---------------- launch ----------------

extern "C" void kernel_launch(void* const* d_in, const int* in_sizes, int n_in,
                              void* d_out, int out_size, void* d_ws, size_t ws_size,
                              hipStream_t stream) {
    const float* hs = (const float*)d_in[0];   // [T,H]
    const float* rw = (const float*)d_in[1];   // [T,E]
    const float* w1 = (const float*)d_in[2];   // [E,H,2D]
    const float* b1 = (const float*)d_in[3];   // [E,2D]
    const float* w3 = (const float*)d_in[4];   // [E,D,H]
    const float* b3 = (const float*)d_in[5];   // [E,H]
    float* out = (float*)d_out;

    char* ws = (char*)d_ws;
    unsigned short* hsb  = (unsigned short*)(ws);                          // 16 MB
    unsigned short* w1b  = (unsigned short*)(ws + ((size_t)16 << 20));     // 32 MB
    unsigned short* w3b  = (unsigned short*)(ws + ((size_t)48 << 20));     // 16 MB
    unsigned short* act2 = (unsigned short*)(ws + ((size_t)64 << 20));     // 128 MB
    // bf16 partials reuse hsb+w1b (dead after gemm1): 3 x 16 MB = 48 MB exactly.
    unsigned short* p0 = (unsigned short*)(ws);
    unsigned short* p1 = (unsigned short*)(ws + ((size_t)16 << 20));
    unsigned short* p2 = (unsigned short*)(ws + ((size_t)32 << 20));

    // 1) hs -> bf16
    {
        size_t n = (size_t)T_DIM * H_DIM;  // 8388608
        f32_to_bf16_kernel<<<dim3(n / (256 * 4)), dim3(256), 0, stream>>>(hs, hsb, n);
    }
    // 2) W1 [E][H][2D] -> w1b [E][2D'][H] bf16 with gate/up 16-col deinterleave
    transpose_conv_kernel<<<dim3(TWO_D / 32, H_DIM / 32, E_DIM), dim3(256), 0, stream>>>(
        w1, w1b, TWO_D, (size_t)H_DIM * TWO_D, (size_t)TWO_D * H_DIM, (size_t)H_DIM, 1);
    // 3) W3 [E][D][H] -> w3b [H][E*D] bf16  (out idx = b*D + c*(E*D) + r)
    transpose_conv_kernel<<<dim3(H_DIM / 32, D_DIM / 32, E_DIM), dim3(256), 0, stream>>>(
        w3, w3b, H_DIM, (size_t)D_DIM * H_DIM, (size_t)D_DIM, (size_t)K2, 0);
    // 4) GEMM1 + GLU epilogue -> act2  (x=m fastest for XCD B-sharing)
    gemm1_kernel<<<dim3(T_DIM / 128, TWO_D / 128, E_DIM), dim3(256), 0, stream>>>(
        (const short*)hsb, (const short*)w1b, b1, rw, (__hip_bfloat16*)act2);
    // 5) GEMM2 split-K=4: slice0 -> out, slices 1-3 -> bf16 partials (dead region)
    gemm2_kernel<<<dim3(8 * 64 * 4), dim3(256), 0, stream>>>(
        (const short*)act2, (const short*)w3b, out, p0, p1, p2);
    // 6) out += p0+p1+p2 + sum_e rw*b3
    reduce_bias_kernel<<<dim3(T_DIM), dim3(H_DIM / 4), 0, stream>>>(
        p0, p1, p2, rw, b3, out);
}